// Round 14
// baseline (145.067 us; speedup 1.0000x reference)
//
#include <hip/hip_runtime.h>
#include <math.h>

#define NIN 91392        // 17*21*16*16
#define DIN 8
#define DOUT 16
#define NCHUNK (NIN / 8) // 11424 chunks of 8 n
#define GRID_P 1024      // 4 blocks/CU persistent
#define TPB 512          // 8 waves; wave w owns n-row w of each chunk

// async global->LDS. LDS dst = wave-uniform base + lane*width; per-lane src.
#define GLD_LDS16(gp, lp) __builtin_amdgcn_global_load_lds(                    \
    (const __attribute__((address_space(1))) float*)(gp),                      \
    (__attribute__((address_space(3))) float*)(lp), 16, 0, 0)
#define GLD_LDS4(gp, lp) __builtin_amdgcn_global_load_lds(                     \
    (const __attribute__((address_space(1))) float*)(gp),                      \
    (__attribute__((address_space(3))) float*)(lp), 4, 0, 0)

// R13 post-mortem: 1-deep prefetch -> ~500cy stall/iter (vmcnt(3) drained a
// DMA issued only ~350cy earlier; HBM ~900cy). THIS KERNEL: depth-2 pipeline.
//  - each slot k = uniform 3-op VMEM set {W-DMA 16B, x-DMA 4B, x-DMA 4B}
//    into per-wave triple buffer (1.5KB/slot); x now in LDS too -> loop has
//    ZERO compiler VMEM, counted vmcnt is exact.
//  - issue set(k+2); s_waitcnt vmcnt(6) keeps sets k+1,k+2 in flight ->
//    every load has 2 compute periods of latency cover (T4).
//  - dummy re-issues (valid addr, dead buf) keep queue uniform; compute
//    guarded by wave-uniform c<NCHUNK.
// lane = (b:4)(og:2); wave owns n-row `wave`; thread holds both j capsules.
// PASS 0: s0 partial = sum_n u. PASS>0: c_j = sigmoid(+-d), d = 2 shuffles.
template<int PASS>
__global__ __launch_bounds__(TPB) void caps_pass(
    const float* __restrict__ x, const float* __restrict__ W,
    const float* __restrict__ vin, float* __restrict__ part, int grid)
{
    const int t = threadIdx.x;
    const int lane = t & 63;
    const int wave = t >> 6;          // 0..7 = n-row within chunk
    const int b  = lane >> 2;         // batch 0..15
    const int og = lane & 3;          // o-group of 4
    const int bid = blockIdx.x;

    // pool: 8 waves x 3 bufs x 384 floats (W 256 + x 128) = 9216 f = 36 KB
    __shared__ __align__(16) float pool[9216];
    float4* pool4 = (float4*)pool;

    // W DMA src: lane l covers j=l>>5 half, f4 slot l&31 of row n (2x512B runs)
    const size_t wsrcl = (size_t)(lane >> 5) * ((size_t)NIN * 128)
                       + (size_t)(lane & 31) * 4;
    // x DMA src (width 4): lane l -> b=l>>2, i-part=l&3
    const size_t xsrcl = (size_t)(lane >> 2) * ((size_t)NIN * 8) + (lane & 3);

    float4 vin0, vin1;                // vin[b][j][og*4..], j = 0 / 1
    if (PASS > 0) {
        vin0 = *(const float4*)(vin + b * 32 + 0  + og * 4);
        vin1 = *(const float4*)(vin + b * 32 + 16 + og * 4);
    }

    float4 accA = make_float4(0.f,0.f,0.f,0.f);   // j=0
    float4 accB = make_float4(0.f,0.f,0.f,0.f);   // j=1

    const int iters = (NCHUNK + grid - 1) / grid;

    // slot issue: one uniform 3-op VMEM set; dummy (c>=NCHUNK) re-reads slot-0
    // addresses into the (dead) target buffer to keep the vmcnt queue uniform.
    #define ISSUE(k) do {                                                      \
        int c_ = bid + (k) * grid;                                             \
        if (c_ >= NCHUNK) c_ = bid;                                            \
        const int n_ = c_ * 8 + wave;                                          \
        float* base_ = pool + wave * 1152 + ((k) % 3) * 384;                   \
        GLD_LDS16(W + (size_t)n_ * 128 + wsrcl, base_);                        \
        GLD_LDS4(x + (size_t)n_ * 8 + xsrcl,     base_ + 256);                 \
        GLD_LDS4(x + (size_t)n_ * 8 + 4 + xsrcl, base_ + 320);                 \
    } while (0)

    ISSUE(0);
    ISSUE(1);

    for (int k = 0; k < iters; ++k) {
        ISSUE(k + 2);                                  // overwrites buf (k-1)%3
        asm volatile("s_waitcnt vmcnt(6)" ::: "memory"); // sets k+1,k+2 in flight
        const int c = bid + k * grid;
        if (c < NCHUNK) {                              // wave-uniform guard
            const float4* wb = pool4 + wave * 288 + (k % 3) * 96;
            // x[b][n] from LDS: f4 idx 64+b (i0..3), 80+b (i4..7); 2-way free
            const float4 xa = wb[64 + b];
            const float4 xc = wb[80 + b];
            const float xr[8] = {xa.x, xa.y, xa.z, xa.w, xc.x, xc.y, xc.z, xc.w};
            float4 u0 = make_float4(0.f,0.f,0.f,0.f);
            float4 u1 = make_float4(0.f,0.f,0.f,0.f);
            #pragma unroll
            for (int i = 0; i < DIN; ++i) {
                const float4 w0 = wb[i * 4 + og];        // j=0, bcast over b
                const float4 w1 = wb[32 + i * 4 + og];   // j=1
                u0.x += xr[i]*w0.x; u0.y += xr[i]*w0.y;
                u0.z += xr[i]*w0.z; u0.w += xr[i]*w0.w;
                u1.x += xr[i]*w1.x; u1.y += xr[i]*w1.y;
                u1.z += xr[i]*w1.z; u1.w += xr[i]*w1.w;
            }

            if (PASS == 0) {
                accA.x += u0.x; accA.y += u0.y; accA.z += u0.z; accA.w += u0.w;
                accB.x += u1.x; accB.y += u1.y; accB.z += u1.z; accB.w += u1.w;
            } else {
                // d = logit0 - logit1, reduced over the 4 og lanes (bits 0..1)
                float m = vin0.x*u0.x + vin0.y*u0.y + vin0.z*u0.z + vin0.w*u0.w
                        - (vin1.x*u1.x + vin1.y*u1.y + vin1.z*u1.z + vin1.w*u1.w);
                m += __shfl_xor(m, 1);
                m += __shfl_xor(m, 2);
                const float c0 = __builtin_amdgcn_rcpf(1.f + __expf(-m));
                const float c1 = __builtin_amdgcn_rcpf(1.f + __expf(m));
                accA.x += c0*u0.x; accA.y += c0*u0.y;
                accA.z += c0*u0.z; accA.w += c0*u0.w;
                accB.x += c1*u1.x; accB.y += c1*u1.y;
                accB.z += c1*u1.z; accB.w += c1*u1.w;
            }
        }
    }
    #undef ISSUE

    // ---- epilogue: cross-wave (n-row) reduce; alias pool (stride-9 pad) ----
    __syncthreads();                  // all waves done reading staging bufs
    {
        float* sl = pool + wave * 576 + lane * 9;
        sl[0]=accA.x; sl[1]=accA.y; sl[2]=accA.z; sl[3]=accA.w;
        sl[4]=accB.x; sl[5]=accB.y; sl[6]=accB.z; sl[7]=accB.w;
    }
    __syncthreads();
    if (t < 64) {
        float s[8];
        #pragma unroll
        for (int k = 0; k < 8; ++k) s[k] = 0.f;
        #pragma unroll
        for (int w = 0; w < 8; ++w) {
            const float* p = pool + w * 576 + t * 9;
            #pragma unroll
            for (int k = 0; k < 8; ++k) s[k] += p[k];
        }
        const int bb = t >> 2, oo = t & 3;
        #pragma unroll
        for (int k = 0; k < 8; ++k) {
            const int j = k >> 2, q = k & 3;
            // column-major partials: part[col][bid]
            part[(size_t)(bb * 32 + j * 16 + oo * 4 + q) * grid + bid] = s[k];
        }
    }
}

// Reduce partials -> s[b,j,o], squash -> v. 32 blocks = one per (b,j).
// PASS 0: scale 0.5 (uniform softmax), write v0
// PASS 1: write v0+v1 (logits linear in accumulated v)
// PASS 2: write final v
template<int PASS>
__global__ __launch_bounds__(256) void caps_reduce(
    const float* __restrict__ part, const float* __restrict__ vprev,
    float* __restrict__ vout, int gridA)
{
    const int blk = blockIdx.x;   // b*2 + j
    const int b = blk >> 1, j = blk & 1;
    const int t = threadIdx.x;
    const int o = t & 15;
    const int ch = t >> 4;
    const size_t base = ((size_t)b * 32 + j * 16 + o) * gridA;
    float s = 0.f;
    for (int g = ch; g < gridA; g += 16) s += part[base + g];
    __shared__ float red[256];
    red[t] = s;
    __syncthreads();
    if (t < 16) {
        float sv = 0.f;
        #pragma unroll
        for (int c = 0; c < 16; ++c) sv += red[c * 16 + t];
        if (PASS == 0) sv *= 0.5f;
        float sq = sv * sv;
        sq += __shfl_xor(sq, 1);
        sq += __shfl_xor(sq, 2);
        sq += __shfl_xor(sq, 4);
        sq += __shfl_xor(sq, 8);
        const float sn = sq;
        float v = sv * sn / ((1.f + sn) * sqrtf(sn + 1e-7f));
        if (PASS == 1) v += vprev[b * 32 + j * 16 + o];
        vout[b * 32 + j * 16 + o] = v;
    }
}

extern "C" void kernel_launch(void* const* d_in, const int* in_sizes, int n_in,
                              void* d_out, int out_size, void* d_ws, size_t ws_size,
                              hipStream_t stream) {
    const float* x = (const float*)d_in[0];
    const float* W = (const float*)d_in[1];
    float* out = (float*)d_out;

    // persistent grid; clamp to workspace (part = 512*GRID floats)
    size_t maxg = (ws_size - 4096) / (512 * sizeof(float));
    int GRID = (int)(maxg < GRID_P ? maxg : GRID_P);
    if (GRID < 1) GRID = 1;

    float* part = (float*)d_ws;                       // 512*GRID floats (2 MB)
    float* v0   = part + (size_t)512 * GRID;          // 512
    float* vsum = v0 + 512;                           // 512

    caps_pass<0><<<GRID, TPB, 0, stream>>>(x, W, nullptr, part, GRID);
    caps_reduce<0><<<32, 256, 0, stream>>>(part, nullptr, v0, GRID);
    caps_pass<1><<<GRID, TPB, 0, stream>>>(x, W, v0, part, GRID);
    caps_reduce<1><<<32, 256, 0, stream>>>(part, v0, vsum, GRID);
    caps_pass<2><<<GRID, TPB, 0, stream>>>(x, W, vsum, part, GRID);
    caps_reduce<2><<<32, 256, 0, stream>>>(part, nullptr, out, GRID);
}

// Round 15
// 143.527 us; speedup vs baseline: 1.0107x; 1.0107x over previous
//
#include <hip/hip_runtime.h>
#include <math.h>

#define NIN 91392        // 17*21*16*16
#define DIN 8
#define DOUT 16
#define NCHUNK (NIN / 8) // 11424 chunks of 8 n
#define GRID_P 768       // 3 blocks/CU (48 KB LDS double-buffer)
#define TPB 512          // 8 waves

// async global->LDS width16: dest = lane-uniform base + lane*16; src per-lane
#define GLD_LDS16(gp, lp) __builtin_amdgcn_global_load_lds(                    \
    (const __attribute__((address_space(1))) float*)(gp),                      \
    (__attribute__((address_space(3))) float*)(lp), 16, 0, 0)

// R14 post-mortem: wall = DS instr count/efficiency (16 W-b128/row serving
// 64B each) + x's scattered 32B global segments. R15:
//  - lane=(b0:3)(j:1)(og:2): thread owns 1 capsule, batches {b0,b0+8}.
//    W reads/row: 8 b128, 128B served each (2j x 4og distinct; j-pair 2-way
//    bank alias = free). d-reduce = 3 shuffles (og,og,j with sign fold).
//  - block-coop round staging (2 chunks/round): W = 16 contiguous-1KB DMAs,
//    x = 8 DMAs of 4x256B runs, SOURCE-swizzled u^=(b&7) (rule #21) so the
//    [b][unit] LDS reads hit 8 disjoint bank-quads (conflict-free).
//  - raw s_barrier + counted vmcnt(3): __syncthreads would drain vmcnt(0)
//    per barrier (m97 stall); this keeps next round's DMAs in flight (T4).
// PASS 0: s0 partial = sum_n u. PASS>0: c_j = sigmoid(sgn_j * d).
template<int PASS>
__global__ __launch_bounds__(TPB) void caps_pass(
    const float* __restrict__ x, const float* __restrict__ W,
    const float* __restrict__ vin, float* __restrict__ part, int grid)
{
    const int t = threadIdx.x;
    const int lane = t & 63;
    const int wave = t >> 6;          // 0..7; owns row `wave` of both chunks
    const int og = lane & 3;          // o-group of 4
    const int j  = (lane >> 2) & 1;   // own capsule
    const int b0 = lane >> 3;         // batches b0, b0+8
    const int bid = blockIdx.x;

    __shared__ __align__(16) float lds[12288];   // W dbuf 8192 + x dbuf 4096

    const float sgn = j ? -1.f : 1.f;

    // --- DMA lane-source precompute (lane-varying parts) ---
    // W instr (m): s=m>>3, p=m&7; lane: R=2p+(lane>>5): 1KB = rows 2p,2p+1
    const int wR_half = lane >> 5;              // row within pair
    const int wFlo = (lane & 31) * 4;           // float offset in 512B row
    // x instr (q=wave): s=q>>2, bg=q&3; lane: b=bg*4+(lane>>4), u'=lane&15
    const int xb = (wave & 3) * 4 + (lane >> 4);
    const int xu = (lane & 15) ^ (xb & 7);      // pre-swizzled source unit
    const int xs = wave >> 2;

    float4 vinA, vinB;                // sgn * vin[b][own j][og*4..]
    if (PASS > 0) {
        float4 a = *(const float4*)(vin + b0 * 32 + j * 16 + og * 4);
        float4 c = *(const float4*)(vin + (b0 + 8) * 32 + j * 16 + og * 4);
        vinA = make_float4(sgn*a.x, sgn*a.y, sgn*a.z, sgn*a.w);
        vinB = make_float4(sgn*c.x, sgn*c.y, sgn*c.z, sgn*c.w);
    }

    float4 accA = make_float4(0.f,0.f,0.f,0.f);   // batch b0
    float4 accB = make_float4(0.f,0.f,0.f,0.f);   // batch b0+8

    // one round = 2 chunks; wave issues 3 DMAs: W m=2w, W m=2w+1, x q=w
    #define ISSUE(k) do {                                                      \
        const int kk = (k); const int bufb = kk & 1;                           \
        { const int m = 2*wave;   const int s = m>>3, p = m&7;                 \
          int c_ = bid + (2*kk + s) * grid; if (c_ >= NCHUNK) c_ = bid;        \
          const int R = 2*p + wR_half;                                         \
          GLD_LDS16(W + (size_t)(R>>3)*(NIN*128)                               \
                      + (size_t)(c_*8 + (R&7))*128 + wFlo,                     \
                    lds + bufb*4096 + s*2048 + p*256); }                       \
        { const int m = 2*wave+1; const int s = m>>3, p = m&7;                 \
          int c_ = bid + (2*kk + s) * grid; if (c_ >= NCHUNK) c_ = bid;        \
          const int R = 2*p + wR_half;                                         \
          GLD_LDS16(W + (size_t)(R>>3)*(NIN*128)                               \
                      + (size_t)(c_*8 + (R&7))*128 + wFlo,                     \
                    lds + bufb*4096 + s*2048 + p*256); }                       \
        { int c_ = bid + (2*kk + xs) * grid; if (c_ >= NCHUNK) c_ = bid;       \
          GLD_LDS16(x + (size_t)xb*(NIN*8) + (size_t)c_*64 + xu*4,             \
                    lds + 8192 + bufb*2048 + xs*1024 + (wave&3)*256); }        \
    } while (0)

    const int R_rounds = (NCHUNK + 2*grid - 1) / (2*grid);

    ISSUE(0);
    ISSUE(1);

    for (int k = 0; k < R_rounds; ++k) {
        asm volatile("s_waitcnt vmcnt(3)" ::: "memory"); // round k's 3 done
        __builtin_amdgcn_s_barrier();                    // all waves' staged

        const int bufb = k & 1;
        #pragma unroll
        for (int s = 0; s < 2; ++s) {
            const int c = bid + (2*k + s) * grid;
            if (c < NCHUNK) {                            // block-uniform guard
                const float* wrow = lds + bufb*4096 + s*2048
                                  + (j*8 + wave)*128 + og*4;
                const float* xrg  = lds + 8192 + bufb*2048 + s*1024;
                const int u0i = wave * 2;                // (n&7)*2, n&7 = wave
                const int swz = (b0 & 7);
                const float4 a0 = *(const float4*)(xrg + b0*64     + ((u0i  )^swz)*4);
                const float4 a1 = *(const float4*)(xrg + b0*64     + ((u0i+1)^swz)*4);
                const float4 c0v= *(const float4*)(xrg + (b0+8)*64 + ((u0i  )^swz)*4);
                const float4 c1v= *(const float4*)(xrg + (b0+8)*64 + ((u0i+1)^swz)*4);
                const float xA[8] = {a0.x,a0.y,a0.z,a0.w,a1.x,a1.y,a1.z,a1.w};
                const float xB[8] = {c0v.x,c0v.y,c0v.z,c0v.w,c1v.x,c1v.y,c1v.z,c1v.w};

                float4 u0 = make_float4(0.f,0.f,0.f,0.f);
                float4 u1 = make_float4(0.f,0.f,0.f,0.f);
                #pragma unroll
                for (int i = 0; i < DIN; ++i) {
                    const float4 w4 = *(const float4*)(wrow + i*16);
                    u0.x += xA[i]*w4.x; u0.y += xA[i]*w4.y;
                    u0.z += xA[i]*w4.z; u0.w += xA[i]*w4.w;
                    u1.x += xB[i]*w4.x; u1.y += xB[i]*w4.y;
                    u1.z += xB[i]*w4.z; u1.w += xB[i]*w4.w;
                }

                if (PASS == 0) {
                    accA.x += u0.x; accA.y += u0.y; accA.z += u0.z; accA.w += u0.w;
                    accB.x += u1.x; accB.y += u1.y; accB.z += u1.z; accB.w += u1.w;
                } else {
                    // m = sgn_j * (vin_j . u_j own og); og-reduce (1,2), j-fold (4)
                    float m0 = vinA.x*u0.x + vinA.y*u0.y + vinA.z*u0.z + vinA.w*u0.w;
                    float m1 = vinB.x*u1.x + vinB.y*u1.y + vinB.z*u1.z + vinB.w*u1.w;
                    m0 += __shfl_xor(m0, 1);  m1 += __shfl_xor(m1, 1);
                    m0 += __shfl_xor(m0, 2);  m1 += __shfl_xor(m1, 2);
                    m0 += __shfl_xor(m0, 4);  m1 += __shfl_xor(m1, 4);  // = d
                    const float cA = __builtin_amdgcn_rcpf(1.f + __expf(-sgn * m0));
                    const float cB = __builtin_amdgcn_rcpf(1.f + __expf(-sgn * m1));
                    accA.x += cA*u0.x; accA.y += cA*u0.y;
                    accA.z += cA*u0.z; accA.w += cA*u0.w;
                    accB.x += cB*u1.x; accB.y += cB*u1.y;
                    accB.z += cB*u1.z; accB.w += cB*u1.w;
                }
            }
        }
        asm volatile("s_waitcnt lgkmcnt(0)" ::: "memory"); // my reads complete
        __builtin_amdgcn_s_barrier();                      // all done reading
        ISSUE(k + 2);                                      // overwrite freed buf
    }
    #undef ISSUE

    // drain all DMAs (incl. tail dummies) before aliasing lds for the reduce
    asm volatile("s_waitcnt vmcnt(0)" ::: "memory");
    __syncthreads();

    // ---- epilogue: cross-wave reduce (8 waves hold disjoint n partials) ----
    {
        float* sl = lds + wave * 576 + lane * 9;
        sl[0]=accA.x; sl[1]=accA.y; sl[2]=accA.z; sl[3]=accA.w;
        sl[4]=accB.x; sl[5]=accB.y; sl[6]=accB.z; sl[7]=accB.w;
    }
    __syncthreads();
    if (t < 64) {
        float s[8];
        #pragma unroll
        for (int q = 0; q < 8; ++q) s[q] = 0.f;
        #pragma unroll
        for (int w = 0; w < 8; ++w) {
            const float* p = lds + w * 576 + t * 9;
            #pragma unroll
            for (int q = 0; q < 8; ++q) s[q] += p[q];
        }
        const int tb0 = t >> 3, tj = (t >> 2) & 1, tog = t & 3;
        #pragma unroll
        for (int q = 0; q < 4; ++q) {
            part[(size_t)(tb0*32 + tj*16 + tog*4 + q) * grid + bid] = s[q];
            part[(size_t)((tb0+8)*32 + tj*16 + tog*4 + q) * grid + bid] = s[4+q];
        }
    }
}

// Reduce partials -> s[b,j,o], squash -> v. 32 blocks = one per (b,j).
// PASS 0: scale 0.5 (uniform softmax), write v0
// PASS 1: write v0+v1 (logits linear in accumulated v)
// PASS 2: write final v
template<int PASS>
__global__ __launch_bounds__(256) void caps_reduce(
    const float* __restrict__ part, const float* __restrict__ vprev,
    float* __restrict__ vout, int gridA)
{
    const int blk = blockIdx.x;   // b*2 + j
    const int b = blk >> 1, j = blk & 1;
    const int t = threadIdx.x;
    const int o = t & 15;
    const int ch = t >> 4;
    const size_t base = ((size_t)b * 32 + j * 16 + o) * gridA;
    float s = 0.f;
    for (int g = ch; g < gridA; g += 16) s += part[base + g];
    __shared__ float red[256];
    red[t] = s;
    __syncthreads();
    if (t < 16) {
        float sv = 0.f;
        #pragma unroll
        for (int c = 0; c < 16; ++c) sv += red[c * 16 + t];
        if (PASS == 0) sv *= 0.5f;
        float sq = sv * sv;
        sq += __shfl_xor(sq, 1);
        sq += __shfl_xor(sq, 2);
        sq += __shfl_xor(sq, 4);
        sq += __shfl_xor(sq, 8);
        const float sn = sq;
        float v = sv * sn / ((1.f + sn) * sqrtf(sn + 1e-7f));
        if (PASS == 1) v += vprev[b * 32 + j * 16 + o];
        vout[b * 32 + j * 16 + o] = v;
    }
}

extern "C" void kernel_launch(void* const* d_in, const int* in_sizes, int n_in,
                              void* d_out, int out_size, void* d_ws, size_t ws_size,
                              hipStream_t stream) {
    const float* x = (const float*)d_in[0];
    const float* W = (const float*)d_in[1];
    float* out = (float*)d_out;

    // grid clamped to workspace (part = 512*GRID floats)
    size_t maxg = (ws_size - 4096) / (512 * sizeof(float));
    int GRID = (int)(maxg < GRID_P ? maxg : GRID_P);
    if (GRID < 1) GRID = 1;

    float* part = (float*)d_ws;                       // 512*GRID floats (1.5 MB)
    float* v0   = part + (size_t)512 * GRID;          // 512
    float* vsum = v0 + 512;                           // 512

    caps_pass<0><<<GRID, TPB, 0, stream>>>(x, W, nullptr, part, GRID);
    caps_reduce<0><<<32, 256, 0, stream>>>(part, nullptr, v0, GRID);
    caps_pass<1><<<GRID, TPB, 0, stream>>>(x, W, v0, part, GRID);
    caps_reduce<1><<<32, 256, 0, stream>>>(part, v0, vsum, GRID);
    caps_pass<2><<<GRID, TPB, 0, stream>>>(x, W, vsum, part, GRID);
    caps_reduce<2><<<32, 256, 0, stream>>>(part, nullptr, out, GRID);
}